// Round 6
// baseline (707.568 us; speedup 1.0000x reference)
//
#include <hip/hip_runtime.h>
#include <hip/hip_bf16.h>
#include <cstdint>
#include <cstddef>

#define D 128
#define NWG 200        // workgroups for edge binning passes

typedef _Float16 f16;
typedef f16 f16x2 __attribute__((ext_vector_type(2)));
typedef f16 f16x4 __attribute__((ext_vector_type(4)));
typedef f16 f16x8 __attribute__((ext_vector_type(8)));
typedef float f32x4 __attribute__((ext_vector_type(4)));
typedef unsigned short u16;

static inline size_t align256(size_t x){ return (x + 255) & ~(size_t)255; }

// ---------------------------------------------------------------------------
// int64 vs int32 edge_index detection (odd dwords of int64 data are all 0)
__global__ void detect_kernel(const int* __restrict__ ei, long long n32, int* __restrict__ flag){
  __shared__ int s;
  if (threadIdx.x == 0) s = 0;
  __syncthreads();
  int nz = 0;
  for (long long i = 2LL*threadIdx.x + 1; i < 4096 && i < n32; i += 512)
    nz |= (ei[i] != 0);
  if (nz) s = 1;
  __syncthreads();
  if (threadIdx.x == 0) *flag = (s ? 0 : 1);   // 1 => int64
}

__device__ __forceinline__ void load_edge(const void* ei, int E, int is64, int e, int& s, int& d){
  if (is64) {
    const long long* p = (const long long*)ei;
    s = (int)p[e]; d = (int)p[(size_t)E + e];
  } else {
    const int* p = (const int*)ei;
    s = p[e]; d = p[(size_t)E + e];
  }
}

// ---------------------------------------------------------------------------
// Pass A: per-(bucket, wg) histogram via LDS counters. No global atomics.
__global__ __launch_bounds__(256) void passA_hist(
    const void* __restrict__ ei, int E, const int* __restrict__ flag,
    int* __restrict__ glob_hist, int NB){
  __shared__ int cnt[256];
  int t = threadIdx.x, wg = blockIdx.x;
  cnt[t] = 0;
  __syncthreads();
  int is64 = *flag;
  int chunk = (E + NWG - 1) / NWG;
  int lo = wg * chunk, hi = min(lo + chunk, E);
  for (int e = lo + t; e < hi; e += 256){
    int s, d;
    load_edge(ei, E, is64, e, s, d);
    atomicAdd(&cnt[d >> 8], 1);
  }
  __syncthreads();
  for (int b = t; b < NB; b += 256)
    glob_hist[b * NWG + wg] = cnt[b];
}

// ---------- generic exclusive scan (3 kernels) ----------
__global__ void scan_partial(const int* __restrict__ src, int* __restrict__ dst,
                             int* __restrict__ blockSums, int L){
  __shared__ int sd[256];
  int t = threadIdx.x;
  int base = blockIdx.x * 1024 + t * 4;
  int v[4]; int s = 0;
  #pragma unroll
  for (int j = 0; j < 4; ++j){ v[j] = (base + j < L) ? src[base + j] : 0; s += v[j]; }
  sd[t] = s; __syncthreads();
  for (int off = 1; off < 256; off <<= 1){
    int x = (t >= off) ? sd[t - off] : 0;
    __syncthreads();
    sd[t] += x;
    __syncthreads();
  }
  int run = sd[t] - s;
  #pragma unroll
  for (int j = 0; j < 4; ++j){
    if (base + j < L) dst[base + j] = run;
    run += v[j];
  }
  if (t == 255) blockSums[blockIdx.x] = sd[255];
}

__global__ void scan_blocksums(int* __restrict__ blockSums, int nblk,
                               int* __restrict__ dst, int L, int total){
  __shared__ int sd[256];
  int t = threadIdx.x;
  int v = (t < nblk) ? blockSums[t] : 0;
  sd[t] = v; __syncthreads();
  for (int off = 1; off < 256; off <<= 1){
    int x = (t >= off) ? sd[t - off] : 0;
    __syncthreads();
    sd[t] += x;
    __syncthreads();
  }
  if (t < nblk) blockSums[t] = sd[t] - v;
  if (t == 0) dst[L] = total;
}

__global__ void scan_add(int* __restrict__ dst, const int* __restrict__ blockSums, int L){
  int i = blockIdx.x * blockDim.x + threadIdx.x;
  if (i >= L) return;
  dst[i] += blockSums[i >> 10];
}

// ---------------------------------------------------------------------------
// Pass B: scatter packed edges (src | dstLow<<16) into bucket-grouped array.
__global__ __launch_bounds__(256) void passB_scatter(
    const void* __restrict__ ei, int E, const int* __restrict__ flag,
    const int* __restrict__ bucketOff, int NB, unsigned* __restrict__ packed){
  __shared__ int cur[256];
  int t = threadIdx.x, wg = blockIdx.x;
  for (int b = t; b < NB; b += 256)
    cur[b] = bucketOff[b * NWG + wg];
  __syncthreads();
  int is64 = *flag;
  int chunk = (E + NWG - 1) / NWG;
  int lo = wg * chunk, hi = min(lo + chunk, E);
  for (int e = lo + t; e < hi; e += 256){
    int s, d;
    load_edge(ei, E, is64, e, s, d);
    int pos = atomicAdd(&cur[d >> 8], 1);
    packed[pos] = (unsigned)s | ((unsigned)(d & 255) << 16);
  }
}

// ---------------------------------------------------------------------------
// Pass C: one wg per bucket. Local counts -> scan -> rowptr/dis -> csr_src(u16).
__global__ __launch_bounds__(256) void passC_csr(
    const unsigned* __restrict__ packed, const int* __restrict__ bucketOff,
    int NB, int N, int E,
    int* __restrict__ rowptr, float* __restrict__ dis, u16* __restrict__ csr_src){
  __shared__ int degl[256];
  __shared__ int sd[256];
  __shared__ int cur[256];
  int t = threadIdx.x, b = blockIdx.x;
  int begin = bucketOff[(size_t)b * NWG];
  int endb  = bucketOff[(size_t)(b + 1) * NWG];
  degl[t] = 0;
  __syncthreads();
  for (int i = begin + t; i < endb; i += 256)
    atomicAdd(&degl[(packed[i] >> 16) & 255], 1);
  __syncthreads();
  int dv = degl[t];
  sd[t] = dv; __syncthreads();
  for (int off = 1; off < 256; off <<= 1){
    int x = (t >= off) ? sd[t - off] : 0;
    __syncthreads();
    sd[t] += x;
    __syncthreads();
  }
  int localOff = sd[t] - dv;
  int v = b * 256 + t;
  if (v < N){
    rowptr[v] = begin + localOff;
    dis[v] = rsqrtf((float)(dv + 1));
  }
  if (b == NB - 1 && t == 0) rowptr[N] = E;
  cur[t] = begin + localOff;
  __syncthreads();
  for (int i = begin + t; i < endb; i += 256){
    unsigned p = packed[i];
    int pos = atomicAdd(&cur[(p >> 16) & 255], 1);
    csr_src[pos] = (u16)(p & 0xFFFFu);
  }
}

// ---------------------------------------------------------------------------
// cast + pre-scale: out[v][c] = f16(in[v][c] * dis[v])
__global__ void cast_scale(const float* __restrict__ in, const float* __restrict__ dis,
                           f16* __restrict__ out, int n4){
  int i = blockIdx.x * blockDim.x + threadIdx.x;
  if (i >= n4) return;
  float dv = dis[i >> 5];
  float4 v = ((const float4*)in)[i];
  f16x4 o; o[0]=(f16)(v.x*dv); o[1]=(f16)(v.y*dv); o[2]=(f16)(v.z*dv); o[3]=(f16)(v.w*dv);
  ((f16x4*)out)[i] = o;
}

// transpose+cast 6 weight matrices: Wt[w][n][k] = W_w[k][n], fp16
__global__ void prep_w(const float* __restrict__ Wa, const float* __restrict__ Wb,
                       const float* __restrict__ Wc, const float* __restrict__ Wd,
                       const float* __restrict__ We, const float* __restrict__ Wf,
                       f16* __restrict__ Wt){
  int i = blockIdx.x * 256 + threadIdx.x;
  int w = i >> 14, rem = i & 16383;
  int n = rem >> 7, k = rem & 127;
  const float* Wp = (w==0)?Wa:(w==1)?Wb:(w==2)?Wc:(w==3)?Wd:(w==4)?We:Wf;
  Wt[i] = (f16)Wp[k*128 + n];
}

// ---------------------------------------------------------------------------
// Channel-sliced aggregation (4 passes x 32 channels), L2-resident gather:
//   out[v][c] = f16( dis[v] * ( sum_{u->v} in[u][c] + in[v][c] ) )
// Pass = blockIdx.x / nodeBlocks (pass-major: one 3.2MB line working set per
// pass stays resident in each XCD's 4MB L2). One wave per node; quarter-wave
// (16 lanes x f16x2 = 64B) gathers one edge -> 4 edges in flight per step,
// 8 with unroll. Streaming data (csr, out) uses non-temporal ops so it does
// not evict the gather lines. Final reduce: shfl_xor 16/32.
__global__ __launch_bounds__(256) void agg_sliced(
    const f16* __restrict__ in, f16* __restrict__ out,
    const int* __restrict__ rowptr, const u16* __restrict__ csr_src,
    const float* __restrict__ dis, int N, int nodeBlocks){
  int bid = blockIdx.x;
  int pass = bid / nodeBlocks;
  int nb   = bid - pass * nodeBlocks;
  int v = nb * 4 + (threadIdx.x >> 6);
  if (v >= N) return;
  int lane = threadIdx.x & 63;
  int q  = lane >> 4;          // quarter-group: which edge of a 4-pack
  int sl = lane & 15;          // channel pair within the 32-ch slice
  int c0 = pass * 32 + sl * 2;
  const f16* base = in + c0;

  int beg = rowptr[v], end = rowptr[v + 1];
  float acc0 = 0.f, acc1 = 0.f;
  int e = beg + q;
  for (; e + 4 < end; e += 8){
    unsigned u0 = __builtin_nontemporal_load(&csr_src[e]);
    unsigned u1 = __builtin_nontemporal_load(&csr_src[e + 4]);
    f16x2 h0 = *(const f16x2*)&base[(size_t)u0 * D];
    f16x2 h1 = *(const f16x2*)&base[(size_t)u1 * D];
    acc0 += (float)h0[0] + (float)h1[0];
    acc1 += (float)h0[1] + (float)h1[1];
  }
  if (e < end){
    unsigned u = __builtin_nontemporal_load(&csr_src[e]);
    f16x2 h = *(const f16x2*)&base[(size_t)u * D];
    acc0 += (float)h[0]; acc1 += (float)h[1];
  }
  // sum the 4 quarter-groups
  acc0 += __shfl_xor(acc0, 16); acc1 += __shfl_xor(acc1, 16);
  acc0 += __shfl_xor(acc0, 32); acc1 += __shfl_xor(acc1, 32);

  if (q == 0){
    float dv = dis[v];
    f16x2 sv = *(const f16x2*)&in[(size_t)v * D + c0];
    f16x2 o;
    o[0] = (f16)((acc0 + (float)sv[0]) * dv);
    o[1] = (f16)((acc1 + (float)sv[1]) * dv);
    __builtin_nontemporal_store(o, (f16x2*)&out[(size_t)v * D + c0]);
  }
}

// ---------------------------------------------------------------------------
// MFMA GEMM (swapped operands): out = A[N,128](fp16) @ W[128,128] + epilogue.
//   EPI 0: fp16 out = relu(AW + b) * dis[r]
//   EPI 1: fp16 out = ((A Wmu + bmu) + eps * exp(A Wls + bls) * 0.1) * dis[r]
//   EPI 2: f32  out = relu(AW + b)            (final layer -> d_out)
template<int EPI>
__global__ __launch_bounds__(512) void gemm_mfma(
    const f16* __restrict__ A, const f16* __restrict__ Wt, const float* __restrict__ bias,
    const f16* __restrict__ Wt2, const float* __restrict__ bias2,
    const float* __restrict__ eps, const float* __restrict__ dis,
    f16* __restrict__ out16, float* __restrict__ outf, int N){

  extern __shared__ __align__(16) f16 Ws[];   // [128][128] (+ second matrix for EPI1)

  int t = threadIdx.x;
  int wave = t >> 6, lane = t & 63;
  int lrow = lane & 15, hi = lane >> 4;
  int r0 = blockIdx.x * 128 + wave * 16;
  bool active = (r0 < N);

  f16x8 a[4];
  if (active){
    int rr = min(r0 + lrow, N - 1);
    const f16* arow = &A[(size_t)rr * D + hi * 8];
    #pragma unroll
    for (int s = 0; s < 4; ++s) a[s] = *(const f16x8*)&arow[s * 32];
  }

  {
    int r = t & 127, p = t >> 7;
    const float4* src = (const float4*)&Wt[r * 128 + p * 32];
    f16* dstrow = &Ws[r * 128];
    #pragma unroll
    for (int i = 0; i < 4; ++i){
      int q = p * 4 + i;
      *(float4*)&dstrow[(q ^ (r & 7)) * 8] = src[i];
    }
    if (EPI == 1){
      const float4* src2 = (const float4*)&Wt2[r * 128 + p * 32];
      f16* dstrow2 = &Ws[16384 + r * 128];
      #pragma unroll
      for (int i = 0; i < 4; ++i){
        int q = p * 4 + i;
        *(float4*)&dstrow2[(q ^ (r & 7)) * 8] = src2[i];
      }
    }
  }
  __syncthreads();
  if (!active) return;

  f32x4 acc[8] = {};
  f32x4 acc2[8] = {};

  #pragma unroll
  for (int s = 0; s < 4; ++s){
    #pragma unroll
    for (int tt = 0; tt < 8; ++tt){
      int n = tt * 16 + lrow;
      int q = (s * 4 + hi) ^ (lrow & 7);
      f16x8 b = *(const f16x8*)&Ws[n * 128 + q * 8];
      acc[tt] = __builtin_amdgcn_mfma_f32_16x16x32_f16(b, a[s], acc[tt], 0, 0, 0);
      if (EPI == 1){
        f16x8 b2 = *(const f16x8*)&Ws[16384 + n * 128 + q * 8];
        acc2[tt] = __builtin_amdgcn_mfma_f32_16x16x32_f16(b2, a[s], acc2[tt], 0, 0, 0);
      }
    }
  }

  int r = r0 + lrow;
  if (r >= N) return;
  float dv = (EPI == 2) ? 1.f : dis[r];
  int cbase = hi * 4;
  #pragma unroll
  for (int tt = 0; tt < 8; ++tt){
    int n0 = tt * 16 + cbase;
    f32x4 bv = *(const f32x4*)&bias[n0];
    if (EPI == 0){
      f16x4 o;
      #pragma unroll
      for (int ii = 0; ii < 4; ++ii)
        o[ii] = (f16)(fmaxf(acc[tt][ii] + bv[ii], 0.f) * dv);
      *(f16x4*)&out16[(size_t)r * D + n0] = o;
    } else if (EPI == 1){
      f32x4 bv2 = *(const f32x4*)&bias2[n0];
      f32x4 e4  = *(const f32x4*)&eps[(size_t)r * D + n0];
      f16x4 o;
      #pragma unroll
      for (int ii = 0; ii < 4; ++ii){
        float mu = acc[tt][ii] + bv[ii];
        float ls = acc2[tt][ii] + bv2[ii];
        o[ii] = (f16)((mu + e4[ii] * __expf(ls) * 0.1f) * dv);
      }
      *(f16x4*)&out16[(size_t)r * D + n0] = o;
    } else {
      f32x4 o;
      #pragma unroll
      for (int ii = 0; ii < 4; ++ii)
        o[ii] = fmaxf(acc[tt][ii] + bv[ii], 0.f);
      *(f32x4*)&outf[(size_t)r * D + n0] = o;
    }
  }
}

// ---------------------------------------------------------------------------
extern "C" void kernel_launch(void* const* d_in, const int* in_sizes, int n_in,
                              void* d_out, int out_size, void* d_ws, size_t ws_size,
                              hipStream_t stream){
  const float* x   = (const float*)d_in[0];
  const void*  ei  = d_in[1];
  const float* eps = (const float*)d_in[2];
  const float* W1  = (const float*)d_in[3];  const float* b1  = (const float*)d_in[4];
  const float* W2  = (const float*)d_in[5];  const float* b2  = (const float*)d_in[6];
  const float* Wmu = (const float*)d_in[7];  const float* bmu = (const float*)d_in[8];
  const float* Wls = (const float*)d_in[9];  const float* bls = (const float*)d_in[10];
  const float* W5  = (const float*)d_in[11]; const float* b5  = (const float*)d_in[12];
  const float* W6  = (const float*)d_in[13]; const float* b6  = (const float*)d_in[14];

  const int N = in_sizes[0] / D;
  const int E = in_sizes[1] / 2;
  const int NB = (N + 255) >> 8;
  const int L  = NB * NWG;
  float* out = (float*)d_out;

  char* ws = (char*)d_ws;
  size_t off = 0;
  auto alloc = [&](size_t bytes){ char* p = ws + off; off += align256(bytes); return p; };
  int*      flag      = (int*)     alloc(256);
  int*      glob_hist = (int*)     alloc(((size_t)L + 1) * 4);
  int*      bucketOff = (int*)     alloc(((size_t)L + 1) * 4);
  int*      blockSums = (int*)     alloc(1024);
  int*      rowptr    = (int*)     alloc(((size_t)N + 1) * 4);
  float*    dis       = (float*)   alloc((size_t)N * 4);
  unsigned* packed    = (unsigned*)alloc((size_t)E * 4);
  u16*      csr_src   = (u16*)     alloc((size_t)E * 2);
  f16*      Wt        = (f16*)     alloc((size_t)6 * 128 * 128 * 2);
  f16*      bufA      = (f16*)     alloc((size_t)N * D * 2);
  f16*      bufB      = (f16*)     alloc((size_t)N * D * 2);
  (void)ws_size; (void)n_in; (void)out_size;

  detect_kernel<<<1, 256, 0, stream>>>((const int*)ei, (long long)2 * E, flag);

  // CSR build: LDS-staged counting sort by dst bucket (no global atomics)
  passA_hist<<<NWG, 256, 0, stream>>>(ei, E, flag, glob_hist, NB);
  int nblk = (L + 1023) / 1024;
  scan_partial<<<nblk, 256, 0, stream>>>(glob_hist, bucketOff, blockSums, L);
  scan_blocksums<<<1, 256, 0, stream>>>(blockSums, nblk, bucketOff, L, E);
  scan_add<<<(L + 255) / 256, 256, 0, stream>>>(bucketOff, blockSums, L);
  passB_scatter<<<NWG, 256, 0, stream>>>(ei, E, flag, bucketOff, NB, packed);
  passC_csr<<<NB, 256, 0, stream>>>(packed, bucketOff, NB, N, E, rowptr, dis, csr_src);

  cast_scale<<<(N * D / 4 + 255) / 256, 256, 0, stream>>>(x, dis, bufB, N * D / 4);
  prep_w<<<(6 * 16384) / 256, 256, 0, stream>>>(W1, W2, Wmu, Wls, W5, W6, Wt);

  int nodeBlocks = (N + 3) / 4;
  int aggGrid = nodeBlocks * 4;              // 4 channel passes, pass-major
  int gemmGrid = (N + 127) / 128;
  size_t lds1 = 128 * 128 * sizeof(f16);     // 32 KB
  size_t lds2 = 2 * 128 * 128 * sizeof(f16); // 64 KB (EPI1)

  // layer 1
  agg_sliced<<<aggGrid, 256, 0, stream>>>(bufB, bufA, rowptr, csr_src, dis, N, nodeBlocks);
  gemm_mfma<0><<<gemmGrid, 512, lds1, stream>>>(bufA, Wt + 0*16384, b1, nullptr, nullptr, nullptr, dis, bufB, nullptr, N);
  // layer 2
  agg_sliced<<<aggGrid, 256, 0, stream>>>(bufB, bufA, rowptr, csr_src, dis, N, nodeBlocks);
  gemm_mfma<0><<<gemmGrid, 512, lds1, stream>>>(bufA, Wt + 1*16384, b2, nullptr, nullptr, nullptr, dis, bufB, nullptr, N);
  // mu/logstd share aggregation; fused reparametrization
  agg_sliced<<<aggGrid, 256, 0, stream>>>(bufB, bufA, rowptr, csr_src, dis, N, nodeBlocks);
  gemm_mfma<1><<<gemmGrid, 512, lds2, stream>>>(bufA, Wt + 2*16384, bmu, Wt + 3*16384, bls, eps, dis, bufB, nullptr, N);
  // layer 5
  agg_sliced<<<aggGrid, 256, 0, stream>>>(bufB, bufA, rowptr, csr_src, dis, N, nodeBlocks);
  gemm_mfma<0><<<gemmGrid, 512, lds1, stream>>>(bufA, Wt + 4*16384, b5, nullptr, nullptr, nullptr, dis, bufB, nullptr, N);
  // layer 6 -> f32 d_out
  agg_sliced<<<aggGrid, 256, 0, stream>>>(bufB, bufA, rowptr, csr_src, dis, N, nodeBlocks);
  gemm_mfma<2><<<gemmGrid, 512, lds1, stream>>>(bufA, Wt + 5*16384, b6, nullptr, nullptr, nullptr, dis, nullptr, out, N);
}

// Round 9
// 385.094 us; speedup vs baseline: 1.8374x; 1.8374x over previous
//
#include <hip/hip_runtime.h>
#include <hip/hip_bf16.h>
#include <cstdint>
#include <cstddef>

#define D 128
#define NWG 200        // workgroups for edge binning passes

typedef _Float16 f16;
typedef f16 f16x2 __attribute__((ext_vector_type(2)));
typedef f16 f16x4 __attribute__((ext_vector_type(4)));
typedef f16 f16x8 __attribute__((ext_vector_type(8)));
typedef float f32x4 __attribute__((ext_vector_type(4)));
typedef unsigned short u16;

static inline size_t align256(size_t x){ return (x + 255) & ~(size_t)255; }

// Inline int64-vs-int32 edge dtype probe: odd dwords of int64 data are all 0.
// Reads dwords 1,3,...,63 (needs E>=32). All lanes agree via ballot.
__device__ __forceinline__ int detect_is64(const void* ei){
  const int* e32 = (const int*)ei;
  int probe = e32[2 * (threadIdx.x & 31) + 1];
  return (__ballot(probe != 0) == 0ULL) ? 1 : 0;
}

__device__ __forceinline__ void load_edge(const void* ei, int E, int is64, int e, int& s, int& d){
  if (is64) {
    const long long* p = (const long long*)ei;
    s = (int)p[e]; d = (int)p[(size_t)E + e];
  } else {
    const int* p = (const int*)ei;
    s = p[e]; d = p[(size_t)E + e];
  }
}

// ---------------------------------------------------------------------------
// Pass A: per-(bucket, wg) histogram via LDS counters. No global atomics.
__global__ __launch_bounds__(256) void passA_hist(
    const void* __restrict__ ei, int E,
    int* __restrict__ glob_hist, int NB){
  __shared__ int cnt[256];
  int t = threadIdx.x, wg = blockIdx.x;
  int is64 = detect_is64(ei);
  cnt[t] = 0;
  __syncthreads();
  int chunk = (E + NWG - 1) / NWG;
  int lo = wg * chunk, hi = min(lo + chunk, E);
  for (int e = lo + t; e < hi; e += 256){
    int s, d;
    load_edge(ei, E, is64, e, s, d);
    atomicAdd(&cnt[d >> 8], 1);
  }
  __syncthreads();
  for (int b = t; b < NB; b += 256)
    glob_hist[b * NWG + wg] = cnt[b];
}

// ---------- generic exclusive scan (partial + blocksums; add folded into readers) ----------
__global__ void scan_partial(const int* __restrict__ src, int* __restrict__ dst,
                             int* __restrict__ blockSums, int L){
  __shared__ int sd[256];
  int t = threadIdx.x;
  int base = blockIdx.x * 1024 + t * 4;
  int v[4]; int s = 0;
  #pragma unroll
  for (int j = 0; j < 4; ++j){ v[j] = (base + j < L) ? src[base + j] : 0; s += v[j]; }
  sd[t] = s; __syncthreads();
  for (int off = 1; off < 256; off <<= 1){
    int x = (t >= off) ? sd[t - off] : 0;
    __syncthreads();
    sd[t] += x;
    __syncthreads();
  }
  int run = sd[t] - s;
  #pragma unroll
  for (int j = 0; j < 4; ++j){
    if (base + j < L) dst[base + j] = run;
    run += v[j];
  }
  if (t == 255) blockSums[blockIdx.x] = sd[255];
}

__global__ void scan_blocksums(int* __restrict__ blockSums, int nblk){
  __shared__ int sd[256];
  int t = threadIdx.x;
  int v = (t < nblk) ? blockSums[t] : 0;
  sd[t] = v; __syncthreads();
  for (int off = 1; off < 256; off <<= 1){
    int x = (t >= off) ? sd[t - off] : 0;
    __syncthreads();
    sd[t] += x;
    __syncthreads();
  }
  if (t < nblk) blockSums[t] = sd[t] - v;   // exclusive
}

// ---------------------------------------------------------------------------
// Pass B: scatter packed edges (src | dstLow<<16) into bucket-grouped array.
// Final offset = bucketOff[i] + blockSums[i>>10] (scan_add folded in).
__global__ __launch_bounds__(256) void passB_scatter(
    const void* __restrict__ ei, int E,
    const int* __restrict__ bucketOff, const int* __restrict__ blockSums,
    int NB, unsigned* __restrict__ packed){
  __shared__ int cur[256];
  int t = threadIdx.x, wg = blockIdx.x;
  int is64 = detect_is64(ei);
  for (int b = t; b < NB; b += 256){
    int i = b * NWG + wg;
    cur[b] = bucketOff[i] + blockSums[i >> 10];
  }
  __syncthreads();
  int chunk = (E + NWG - 1) / NWG;
  int lo = wg * chunk, hi = min(lo + chunk, E);
  for (int e = lo + t; e < hi; e += 256){
    int s, d;
    load_edge(ei, E, is64, e, s, d);
    int pos = atomicAdd(&cur[d >> 8], 1);
    packed[pos] = (unsigned)s | ((unsigned)(d & 255) << 16);
  }
}

// ---------------------------------------------------------------------------
// Pass C: one wg per bucket. Local counts -> scan -> rowptr/dis -> csr_src(u16).
__global__ __launch_bounds__(256) void passC_csr(
    const unsigned* __restrict__ packed, const int* __restrict__ bucketOff,
    const int* __restrict__ blockSums, int NB, int N, int E,
    int* __restrict__ rowptr, float* __restrict__ dis, u16* __restrict__ csr_src){
  __shared__ int degl[256];
  __shared__ int sd[256];
  __shared__ int cur[256];
  int t = threadIdx.x, b = blockIdx.x;
  int i0 = b * NWG, i1 = (b + 1) * NWG;
  int begin = bucketOff[i0] + blockSums[i0 >> 10];
  int endb  = (b == NB - 1) ? E : (bucketOff[i1] + blockSums[i1 >> 10]);
  degl[t] = 0;
  __syncthreads();
  for (int i = begin + t; i < endb; i += 256)
    atomicAdd(&degl[(packed[i] >> 16) & 255], 1);
  __syncthreads();
  int dv = degl[t];
  sd[t] = dv; __syncthreads();
  for (int off = 1; off < 256; off <<= 1){
    int x = (t >= off) ? sd[t - off] : 0;
    __syncthreads();
    sd[t] += x;
    __syncthreads();
  }
  int localOff = sd[t] - dv;
  int v = b * 256 + t;
  if (v < N){
    rowptr[v] = begin + localOff;
    dis[v] = rsqrtf((float)(dv + 1));
  }
  if (b == NB - 1 && t == 0) rowptr[N] = E;
  cur[t] = begin + localOff;
  __syncthreads();
  for (int i = begin + t; i < endb; i += 256){
    unsigned p = packed[i];
    int pos = atomicAdd(&cur[(p >> 16) & 255], 1);
    csr_src[pos] = (u16)(p & 0xFFFFu);
  }
}

// ---------------------------------------------------------------------------
// cast + pre-scale: out[v][c] = f16(in[v][c] * dis[v])
__global__ void cast_scale(const float* __restrict__ in, const float* __restrict__ dis,
                           f16* __restrict__ out, int n4){
  int i = blockIdx.x * blockDim.x + threadIdx.x;
  if (i >= n4) return;
  float dv = dis[i >> 5];
  float4 v = ((const float4*)in)[i];
  f16x4 o; o[0]=(f16)(v.x*dv); o[1]=(f16)(v.y*dv); o[2]=(f16)(v.z*dv); o[3]=(f16)(v.w*dv);
  ((f16x4*)out)[i] = o;
}

// transpose+cast 6 weight matrices: Wt[w][n][k] = W_w[k][n], fp16
__global__ void prep_w(const float* __restrict__ Wa, const float* __restrict__ Wb,
                       const float* __restrict__ Wc, const float* __restrict__ Wd,
                       const float* __restrict__ We, const float* __restrict__ Wf,
                       f16* __restrict__ Wt){
  int i = blockIdx.x * 256 + threadIdx.x;
  int w = i >> 14, rem = i & 16383;
  int n = rem >> 7, k = rem & 127;
  const float* Wp = (w==0)?Wa:(w==1)?Wb:(w==2)?Wc:(w==3)?Wd:(w==4)?We:Wf;
  Wt[i] = (f16)Wp[k*128 + n];
}

// ---------------------------------------------------------------------------
// unweighted fp16 aggregation over pre-scaled activations:
//   out[v] = f16( dis[v] * ( sum_{u->v} in[u] + in[v] ) )
// wave per node; lane covers channels 2c,2c+1. 16 gathers in flight per batch;
// remainder handled as a full masked 16-batch (clamped wave-uniform indices ->
// redundant loads re-hit the same line; predicated accumulate). NT on the
// index stream and output so streams don't evict the gather working set.
__global__ __launch_bounds__(256) void agg16(
    const f16* __restrict__ in, f16* __restrict__ out,
    const int* __restrict__ rowptr, const u16* __restrict__ csr_src,
    const float* __restrict__ dis, int N){
  int v = blockIdx.x * 4 + (threadIdx.x >> 6);
  if (v >= N) return;
  int c2 = (threadIdx.x & 63) * 2;
  float dv = dis[v];
  int beg = rowptr[v], end = rowptr[v + 1];
  f16x2 sv = *(const f16x2*)&in[(size_t)v * D + c2];
  float acc0 = (float)sv[0], acc1 = (float)sv[1];
  int e = beg;
  for (; e + 15 < end; e += 16){
    f16x2 h[16];
    #pragma unroll
    for (int j = 0; j < 16; ++j){
      unsigned u = __builtin_nontemporal_load(&csr_src[e + j]);
      h[j] = *(const f16x2*)&in[(size_t)u * D + c2];
    }
    #pragma unroll
    for (int j = 0; j < 16; ++j){ acc0 += (float)h[j][0]; acc1 += (float)h[j][1]; }
  }
  int rem = end - e;
  if (rem > 0){
    int last = end - 1;
    f16x2 h[16];
    #pragma unroll
    for (int j = 0; j < 16; ++j){
      int idx = e + j;
      idx = idx > last ? last : idx;
      unsigned u = __builtin_nontemporal_load(&csr_src[idx]);
      h[j] = *(const f16x2*)&in[(size_t)u * D + c2];
    }
    #pragma unroll
    for (int j = 0; j < 16; ++j){
      acc0 += (j < rem) ? (float)h[j][0] : 0.f;
      acc1 += (j < rem) ? (float)h[j][1] : 0.f;
    }
  }
  f16x2 o; o[0] = (f16)(acc0 * dv); o[1] = (f16)(acc1 * dv);
  __builtin_nontemporal_store(o, (f16x2*)&out[(size_t)v * D + c2]);
}

// ---------------------------------------------------------------------------
// MFMA GEMM (swapped operands): out = A[N,128](fp16) @ W[128,128] + epilogue.
//   EPI 0: fp16 out = relu(AW + b) * dis[r]
//   EPI 1: fp16 out = ((A Wmu + bmu) + eps * exp(A Wls + bls) * 0.1) * dis[r]
//   EPI 2: f32  out = relu(AW + b)            (final layer -> d_out)
// Block = 512 thr = 8 waves, 128 rows/block; W (Wt[n][k]) staged once in LDS
// with 16B-quad XOR swizzle. Per wave: 16 rows x 128 cols.
// mfma(X=Wt-slice, Y=A-rows): lane holds OUT[r0+(l&15)][n0+(l>>4)*4+ii].
template<int EPI>
__global__ __launch_bounds__(512) void gemm_mfma(
    const f16* __restrict__ A, const f16* __restrict__ Wt, const float* __restrict__ bias,
    const f16* __restrict__ Wt2, const float* __restrict__ bias2,
    const float* __restrict__ eps, const float* __restrict__ dis,
    f16* __restrict__ out16, float* __restrict__ outf, int N){

  extern __shared__ __align__(16) f16 Ws[];   // [128][128] (+ second matrix for EPI1)

  int t = threadIdx.x;
  int wave = t >> 6, lane = t & 63;
  int lrow = lane & 15, hi = lane >> 4;
  int r0 = blockIdx.x * 128 + wave * 16;
  bool active = (r0 < N);

  f16x8 a[4];
  if (active){
    int rr = min(r0 + lrow, N - 1);
    const f16* arow = &A[(size_t)rr * D + hi * 8];
    #pragma unroll
    for (int s = 0; s < 4; ++s) a[s] = *(const f16x8*)&arow[s * 32];
  }

  {
    int r = t & 127, p = t >> 7;
    const float4* src = (const float4*)&Wt[r * 128 + p * 32];
    f16* dstrow = &Ws[r * 128];
    #pragma unroll
    for (int i = 0; i < 4; ++i){
      int q = p * 4 + i;
      *(float4*)&dstrow[(q ^ (r & 7)) * 8] = src[i];
    }
    if (EPI == 1){
      const float4* src2 = (const float4*)&Wt2[r * 128 + p * 32];
      f16* dstrow2 = &Ws[16384 + r * 128];
      #pragma unroll
      for (int i = 0; i < 4; ++i){
        int q = p * 4 + i;
        *(float4*)&dstrow2[(q ^ (r & 7)) * 8] = src2[i];
      }
    }
  }
  __syncthreads();
  if (!active) return;

  f32x4 acc[8] = {};
  f32x4 acc2[8] = {};

  #pragma unroll
  for (int s = 0; s < 4; ++s){
    #pragma unroll
    for (int tt = 0; tt < 8; ++tt){
      int n = tt * 16 + lrow;
      int q = (s * 4 + hi) ^ (lrow & 7);
      f16x8 b = *(const f16x8*)&Ws[n * 128 + q * 8];
      acc[tt] = __builtin_amdgcn_mfma_f32_16x16x32_f16(b, a[s], acc[tt], 0, 0, 0);
      if (EPI == 1){
        f16x8 b2 = *(const f16x8*)&Ws[16384 + n * 128 + q * 8];
        acc2[tt] = __builtin_amdgcn_mfma_f32_16x16x32_f16(b2, a[s], acc2[tt], 0, 0, 0);
      }
    }
  }

  int r = r0 + lrow;
  if (r >= N) return;
  float dv = (EPI == 2) ? 1.f : dis[r];
  int cbase = hi * 4;
  #pragma unroll
  for (int tt = 0; tt < 8; ++tt){
    int n0 = tt * 16 + cbase;
    f32x4 bv = *(const f32x4*)&bias[n0];
    if (EPI == 0){
      f16x4 o;
      #pragma unroll
      for (int ii = 0; ii < 4; ++ii)
        o[ii] = (f16)(fmaxf(acc[tt][ii] + bv[ii], 0.f) * dv);
      *(f16x4*)&out16[(size_t)r * D + n0] = o;
    } else if (EPI == 1){
      f32x4 bv2 = *(const f32x4*)&bias2[n0];
      f32x4 e4  = *(const f32x4*)&eps[(size_t)r * D + n0];
      f16x4 o;
      #pragma unroll
      for (int ii = 0; ii < 4; ++ii){
        float mu = acc[tt][ii] + bv[ii];
        float ls = acc2[tt][ii] + bv2[ii];
        o[ii] = (f16)((mu + e4[ii] * __expf(ls) * 0.1f) * dv);
      }
      *(f16x4*)&out16[(size_t)r * D + n0] = o;
    } else {
      f32x4 o;
      #pragma unroll
      for (int ii = 0; ii < 4; ++ii)
        o[ii] = fmaxf(acc[tt][ii] + bv[ii], 0.f);
      *(f32x4*)&outf[(size_t)r * D + n0] = o;
    }
  }
}

// ---------------------------------------------------------------------------
extern "C" void kernel_launch(void* const* d_in, const int* in_sizes, int n_in,
                              void* d_out, int out_size, void* d_ws, size_t ws_size,
                              hipStream_t stream){
  const float* x   = (const float*)d_in[0];
  const void*  ei  = d_in[1];
  const float* eps = (const float*)d_in[2];
  const float* W1  = (const float*)d_in[3];  const float* b1  = (const float*)d_in[4];
  const float* W2  = (const float*)d_in[5];  const float* b2  = (const float*)d_in[6];
  const float* Wmu = (const float*)d_in[7];  const float* bmu = (const float*)d_in[8];
  const float* Wls = (const float*)d_in[9];  const float* bls = (const float*)d_in[10];
  const float* W5  = (const float*)d_in[11]; const float* b5  = (const float*)d_in[12];
  const float* W6  = (const float*)d_in[13]; const float* b6  = (const float*)d_in[14];

  const int N = in_sizes[0] / D;
  const int E = in_sizes[1] / 2;
  const int NB = (N + 255) >> 8;
  const int L  = NB * NWG;
  float* out = (float*)d_out;

  char* ws = (char*)d_ws;
  size_t off = 0;
  auto alloc = [&](size_t bytes){ char* p = ws + off; off += align256(bytes); return p; };
  int*      glob_hist = (int*)     alloc(((size_t)L + 1) * 4);
  int*      bucketOff = (int*)     alloc(((size_t)L + 1) * 4);
  int*      blockSums = (int*)     alloc(1024);
  int*      rowptr    = (int*)     alloc(((size_t)N + 1) * 4);
  float*    dis       = (float*)   alloc((size_t)N * 4);
  unsigned* packed    = (unsigned*)alloc((size_t)E * 4);
  u16*      csr_src   = (u16*)     alloc((size_t)E * 2);
  f16*      Wt        = (f16*)     alloc((size_t)6 * 128 * 128 * 2);
  f16*      bufA      = (f16*)     alloc((size_t)N * D * 2);
  f16*      bufB      = (f16*)     alloc((size_t)N * D * 2);
  (void)ws_size; (void)n_in; (void)out_size;

  // CSR build: LDS-staged counting sort by dst bucket (no global atomics)
  passA_hist<<<NWG, 256, 0, stream>>>(ei, E, glob_hist, NB);
  int nblk = (L + 1023) / 1024;
  scan_partial<<<nblk, 256, 0, stream>>>(glob_hist, bucketOff, blockSums, L);
  scan_blocksums<<<1, 256, 0, stream>>>(blockSums, nblk);
  passB_scatter<<<NWG, 256, 0, stream>>>(ei, E, bucketOff, blockSums, NB, packed);
  passC_csr<<<NB, 256, 0, stream>>>(packed, bucketOff, blockSums, NB, N, E, rowptr, dis, csr_src);

  cast_scale<<<(N * D / 4 + 255) / 256, 256, 0, stream>>>(x, dis, bufB, N * D / 4);
  prep_w<<<(6 * 16384) / 256, 256, 0, stream>>>(W1, W2, Wmu, Wls, W5, W6, Wt);

  int aggGrid = (N + 3) / 4;
  int gemmGrid = (N + 127) / 128;
  size_t lds1 = 128 * 128 * sizeof(f16);     // 32 KB
  size_t lds2 = 2 * 128 * 128 * sizeof(f16); // 64 KB (EPI1)

  // layer 1
  agg16<<<aggGrid, 256, 0, stream>>>(bufB, bufA, rowptr, csr_src, dis, N);
  gemm_mfma<0><<<gemmGrid, 512, lds1, stream>>>(bufA, Wt + 0*16384, b1, nullptr, nullptr, nullptr, dis, bufB, nullptr, N);
  // layer 2
  agg16<<<aggGrid, 256, 0, stream>>>(bufB, bufA, rowptr, csr_src, dis, N);
  gemm_mfma<0><<<gemmGrid, 512, lds1, stream>>>(bufA, Wt + 1*16384, b2, nullptr, nullptr, nullptr, dis, bufB, nullptr, N);
  // mu/logstd share aggregation; fused reparametrization
  agg16<<<aggGrid, 256, 0, stream>>>(bufB, bufA, rowptr, csr_src, dis, N);
  gemm_mfma<1><<<gemmGrid, 512, lds2, stream>>>(bufA, Wt + 2*16384, bmu, Wt + 3*16384, bls, eps, dis, bufB, nullptr, N);
  // layer 5
  agg16<<<aggGrid, 256, 0, stream>>>(bufB, bufA, rowptr, csr_src, dis, N);
  gemm_mfma<0><<<gemmGrid, 512, lds1, stream>>>(bufA, Wt + 4*16384, b5, nullptr, nullptr, nullptr, dis, bufB, nullptr, N);
  // layer 6 -> f32 d_out
  agg16<<<aggGrid, 256, 0, stream>>>(bufB, bufA, rowptr, csr_src, dis, N);
  gemm_mfma<2><<<gemmGrid, 512, lds1, stream>>>(bufA, Wt + 5*16384, b6, nullptr, nullptr, nullptr, dis, nullptr, out, N);
}